// Round 2
// baseline (4528.770 us; speedup 1.0000x reference)
//
#include <hip/hip_runtime.h>
#include <math.h>

#define B 4096
#define D 128
#define TWO_D 256
#define S_SLOTS 16
#define NSYM 128
#define V_OUT 128
#define T_STEPS 8
#define EPS 1e-6f
#define ACT_TH 0.9999f
#define GBS 0.8f
#define CC 0.01f
#define SCALE 0.08838834764831845f  // D^-0.5

#define NCHUNK 4
#define CHUNK_KEYS (B / NCHUNK)  // 1024

// ---------------------------------------------------------------------------
// build combined real-ified complex weights:  out = [inr,ini] @ W'^T
// W' = [[Wr, -Wi],[Wi, Wr]]  (256x256, row-major)
// ---------------------------------------------------------------------------
__device__ __forceinline__ float combine_w(const float* __restrict__ Wr,
                                           const float* __restrict__ Wi,
                                           int j, int k) {
  if (j < D) return (k < D) ? Wr[j * D + k] : -Wi[j * D + (k - D)];
  return (k < D) ? Wi[(j - D) * D + k] : Wr[(j - D) * D + (k - D)];
}

__global__ __launch_bounds__(256) void build_weights(
    const float* __restrict__ cell_Wr, const float* __restrict__ cell_Wi,
    const float* __restrict__ Wq_r, const float* __restrict__ Wq_i,
    const float* __restrict__ Wk_r, const float* __restrict__ Wk_i,
    const float* __restrict__ Wv_r, const float* __restrict__ Wv_i,
    const float* __restrict__ codebook,
    float* __restrict__ cellW, float* __restrict__ qkvW,
    float* __restrict__ cbsq) {
  int e = blockIdx.x * 256 + threadIdx.x;  // 0..65535
  int j = e >> 8, k = e & 255;
  cellW[e] = combine_w(cell_Wr, cell_Wi, j, k);
  qkvW[e] = combine_w(Wq_r, Wq_i, j, k);
  qkvW[65536 + e] = combine_w(Wk_r, Wk_i, j, k);
  qkvW[131072 + e] = combine_w(Wv_r, Wv_i, j, k);
  if (blockIdx.x == 0 && threadIdx.x < NSYM) {
    float s = 0.f;
    for (int c = 0; c < TWO_D; c++) {
      float v = codebook[threadIdx.x * TWO_D + c];
      s += v * v;
    }
    cbsq[threadIdx.x] = s;
  }
}

// ---------------------------------------------------------------------------
// init: embedding -> zf ; zero zw/stack ; ptr one-hot ; scalars
// ---------------------------------------------------------------------------
__global__ __launch_bounds__(128) void init_state(
    const int* __restrict__ input_ids, const float* __restrict__ emb_mag,
    const float* __restrict__ emb_phase, float* __restrict__ zf,
    float* __restrict__ ptrb, float* __restrict__ halting,
    float* __restrict__ remain, float* __restrict__ vq,
    float* __restrict__ eth, float* __restrict__ ponder,
    float* __restrict__ zw, float* __restrict__ stack) {
  int b = blockIdx.x, tid = threadIdx.x;
  int idx = input_ids[b];
  float rr = emb_mag[idx * D + tid];
  float th = emb_phase[idx * D + tid];
  zf[(size_t)b * TWO_D + tid] = rr * cosf(th);
  zf[(size_t)b * TWO_D + D + tid] = rr * sinf(th);
  zw[(size_t)b * TWO_D + tid] = 0.f;
  zw[(size_t)b * TWO_D + D + tid] = 0.f;
  if (tid < S_SLOTS) ptrb[b * S_SLOTS + tid] = (tid == 0) ? 1.f : 0.f;
  if (tid == 0) {
    halting[b] = 0.f; remain[b] = 1.f;
    vq[b] = 0.f; eth[b] = 0.f; ponder[b] = 0.f;
  }
  for (int k = tid; k < S_SLOTS * TWO_D; k += 128)
    stack[(size_t)b * S_SLOTS * TWO_D + k] = 0.f;
}

// ---------------------------------------------------------------------------
// GEMM: C[m][n] = sum_k A[m][k] * W[n][k]   A: Bx256, W: Nx256 (row-major)
// grid (B/64, N/64), 256 threads, 64x64 tile, 4x4 per thread.
// For N>256 (fused qkv) the output is split into consecutive Bx256 buffers.
// ---------------------------------------------------------------------------
#define STAGE_T(dst, src, rowbase)                                            \
  do {                                                                        \
    const float4 _x0 =                                                        \
        *(const float4*)&src[(size_t)((rowbase) + r) * TWO_D + kk0 + kq];     \
    const float4 _x1 =                                                        \
        *(const float4*)&src[(size_t)((rowbase) + r + 32) * TWO_D + kk0 + kq];\
    dst[kq + 0][r] = _x0.x; dst[kq + 1][r] = _x0.y;                           \
    dst[kq + 2][r] = _x0.z; dst[kq + 3][r] = _x0.w;                           \
    dst[kq + 0][r + 32] = _x1.x; dst[kq + 1][r + 32] = _x1.y;                 \
    dst[kq + 2][r + 32] = _x1.z; dst[kq + 3][r + 32] = _x1.w;                 \
  } while (0)

__global__ __launch_bounds__(256) void gemm_rowmajor_bt(
    const float* __restrict__ A, const float* __restrict__ W,
    float* __restrict__ C) {
  __shared__ float As[32][68];   // stride 68 -> 16B-aligned rows
  __shared__ float Wsm[32][68];
  const int m0 = blockIdx.x * 64;
  const int n0g = blockIdx.y * 64;
  const int buf = n0g >> 8;
  const int n0 = n0g & 255;
  const int tid = threadIdx.x;
  const int ty = tid >> 4, tx = tid & 15;
  const int r = tid >> 3, kq = (tid & 7) << 2;
  float acc[4][4] = {};
  for (int kk0 = 0; kk0 < TWO_D; kk0 += 32) {
    STAGE_T(As, A, m0);
    STAGE_T(Wsm, W, n0g);
    __syncthreads();
#pragma unroll
    for (int k = 0; k < 32; k++) {
      float4 av = *(const float4*)&As[k][ty << 2];
      float4 bv = *(const float4*)&Wsm[k][tx << 2];
      float a[4] = {av.x, av.y, av.z, av.w};
      float bb[4] = {bv.x, bv.y, bv.z, bv.w};
#pragma unroll
      for (int i = 0; i < 4; i++)
#pragma unroll
        for (int j = 0; j < 4; j++) acc[i][j] = fmaf(a[i], bb[j], acc[i][j]);
    }
    __syncthreads();
  }
  float* Cb = C + (size_t)buf * B * TWO_D;
#pragma unroll
  for (int i = 0; i < 4; i++) {
    float4 o = make_float4(acc[i][0], acc[i][1], acc[i][2], acc[i][3]);
    *(float4*)&Cb[(size_t)(m0 + (ty << 2) + i) * TWO_D + n0 + (tx << 2)] = o;
  }
}

// ---------------------------------------------------------------------------
// cnorm + modrelu, one 128-thread block per row (in-place on pf)
// ---------------------------------------------------------------------------
__global__ __launch_bounds__(128) void cnorm_modrelu(
    float* __restrict__ pf, const float* __restrict__ ln_scale,
    const float* __restrict__ ln_shift, const float* __restrict__ mod_bias) {
  int b = blockIdx.x, d = threadIdx.x;
  __shared__ float red[128];
  float pr = pf[(size_t)b * TWO_D + d];
  float pi = pf[(size_t)b * TWO_D + D + d];
  float h2 = pr * pr + pi * pi;
  float h = sqrtf(h2);
  float mag = h + EPS;
  red[d] = mag;
  __syncthreads();
  for (int s = 64; s > 0; s >>= 1) {
    if (d < s) red[d] += red[d + s];
    __syncthreads();
  }
  float mean = red[0] * (1.f / 128.f);
  __syncthreads();
  float dm = mag - mean;
  red[d] = dm * dm;
  __syncthreads();
  for (int s = 64; s > 0; s >>= 1) {
    if (d < s) red[d] += red[d + s];
    __syncthreads();
  }
  float var = red[0] * (1.f / 127.f);
  float nm = dm * (1.f / sqrtf(var + EPS)) * ln_scale[d] + ln_shift[d];
  float cph, sph;
  if (h > 0.f) { cph = pr / h; sph = pi / h; } else { cph = 1.f; sph = 0.f; }
  float zr = nm * cph, zi = nm * sph;
  float norm = sqrtf(zr * zr + zi * zi) + EPS;
  float s = fmaxf(norm + mod_bias[d], 0.f) / norm;
  pf[(size_t)b * TWO_D + d] = zr * s;
  pf[(size_t)b * TWO_D + D + d] = zi * s;
}

// ---------------------------------------------------------------------------
// split-K flash attention (f32). grid (B/64, NCHUNK), 256 threads.
// Each block: 64 q-rows x 1024 keys, online softmax, partial (O,m,l) out.
// ---------------------------------------------------------------------------
__global__ __launch_bounds__(256) void flash_attn(
    const float* __restrict__ qf, const float* __restrict__ kf,
    const float* __restrict__ vf, float* __restrict__ Opart,
    float* __restrict__ mpart, float* __restrict__ lpart) {
  __shared__ float Qs[32][68];
  __shared__ float Ks[32][68];
  __shared__ float Ps[64][68];
  __shared__ float Vs[16][260];
  const int q0 = blockIdx.x * 64;
  const int chunk = blockIdx.y;
  const int tid = threadIdx.x;
  const int ty = tid >> 4, tx = tid & 15;
  const int r = tid >> 3, kq = (tid & 7) << 2;

  float O[4][16];
  float m_i[4], l_i[4];
#pragma unroll
  for (int i = 0; i < 4; i++) {
    m_i[i] = -1e30f; l_i[i] = 0.f;
#pragma unroll
    for (int c = 0; c < 16; c++) O[i][c] = 0.f;
  }

  for (int j0 = chunk * CHUNK_KEYS; j0 < (chunk + 1) * CHUNK_KEYS; j0 += 64) {
    float Sacc[4][4] = {};
    for (int kk0 = 0; kk0 < TWO_D; kk0 += 32) {
      STAGE_T(Qs, qf, q0);
      STAGE_T(Ks, kf, j0);
      __syncthreads();
#pragma unroll
      for (int k = 0; k < 32; k++) {
        float4 av = *(const float4*)&Qs[k][ty << 2];
        float4 bv = *(const float4*)&Ks[k][tx << 2];
        float a[4] = {av.x, av.y, av.z, av.w};
        float bb[4] = {bv.x, bv.y, bv.z, bv.w};
#pragma unroll
        for (int i = 0; i < 4; i++)
#pragma unroll
          for (int j = 0; j < 4; j++)
            Sacc[i][j] = fmaf(a[i], bb[j], Sacc[i][j]);
      }
      __syncthreads();
    }
    // online softmax update (rows: ty*4+i ; 16 lanes per row share ty)
#pragma unroll
    for (int i = 0; i < 4; i++) {
#pragma unroll
      for (int j = 0; j < 4; j++) Sacc[i][j] *= SCALE;
      float mm = fmaxf(fmaxf(Sacc[i][0], Sacc[i][1]),
                       fmaxf(Sacc[i][2], Sacc[i][3]));
      for (int off = 1; off < 16; off <<= 1)
        mm = fmaxf(mm, __shfl_xor(mm, off));
      float mnew = fmaxf(m_i[i], mm);
      float corr = expf(m_i[i] - mnew);
      float rs = 0.f;
      float p[4];
#pragma unroll
      for (int j = 0; j < 4; j++) {
        p[j] = expf(Sacc[i][j] - mnew);
        rs += p[j];
      }
      for (int off = 1; off < 16; off <<= 1) rs += __shfl_xor(rs, off);
      l_i[i] = l_i[i] * corr + rs;
#pragma unroll
      for (int c = 0; c < 16; c++) O[i][c] *= corr;
      m_i[i] = mnew;
#pragma unroll
      for (int j = 0; j < 4; j++) Ps[(ty << 2) + i][(tx << 2) + j] = p[j];
    }
    __syncthreads();
    // O += P @ V
    for (int vk0 = 0; vk0 < 64; vk0 += 16) {
      {
        int vr_ = tid >> 4;
        int vc = (tid & 15) << 4;
        const float* src = &vf[(size_t)(j0 + vk0 + vr_) * TWO_D + vc];
        float4 x0 = *(const float4*)&src[0];
        float4 x1 = *(const float4*)&src[4];
        float4 x2 = *(const float4*)&src[8];
        float4 x3 = *(const float4*)&src[12];
        *(float4*)&Vs[vr_][vc + 0] = x0;
        *(float4*)&Vs[vr_][vc + 4] = x1;
        *(float4*)&Vs[vr_][vc + 8] = x2;
        *(float4*)&Vs[vr_][vc + 12] = x3;
      }
      __syncthreads();
#pragma unroll
      for (int kk = 0; kk < 16; kk++) {
        float pv[4];
#pragma unroll
        for (int i = 0; i < 4; i++) pv[i] = Ps[(ty << 2) + i][vk0 + kk];
        float4 v0 = *(const float4*)&Vs[kk][(tx << 4) + 0];
        float4 v1 = *(const float4*)&Vs[kk][(tx << 4) + 4];
        float4 v2 = *(const float4*)&Vs[kk][(tx << 4) + 8];
        float4 v3 = *(const float4*)&Vs[kk][(tx << 4) + 12];
        float vv[16] = {v0.x, v0.y, v0.z, v0.w, v1.x, v1.y, v1.z, v1.w,
                        v2.x, v2.y, v2.z, v2.w, v3.x, v3.y, v3.z, v3.w};
#pragma unroll
        for (int i = 0; i < 4; i++)
#pragma unroll
          for (int c = 0; c < 16; c++)
            O[i][c] = fmaf(pv[i], vv[c], O[i][c]);
      }
      __syncthreads();
    }
  }
#pragma unroll
  for (int i = 0; i < 4; i++) {
    int row = q0 + (ty << 2) + i;
    if (tx == 0) {
      mpart[chunk * B + row] = m_i[i];
      lpart[chunk * B + row] = l_i[i];
    }
    float* dst = &Opart[((size_t)chunk * B + row) * TWO_D + (tx << 4)];
    *(float4*)&dst[0] = make_float4(O[i][0], O[i][1], O[i][2], O[i][3]);
    *(float4*)&dst[4] = make_float4(O[i][4], O[i][5], O[i][6], O[i][7]);
    *(float4*)&dst[8] = make_float4(O[i][8], O[i][9], O[i][10], O[i][11]);
    *(float4*)&dst[12] = make_float4(O[i][12], O[i][13], O[i][14], O[i][15]);
  }
}

__global__ __launch_bounds__(256) void merge_attn(
    const float* __restrict__ Opart, const float* __restrict__ mpart,
    const float* __restrict__ lpart, float* __restrict__ af) {
  int b = blockIdx.x, c = threadIdx.x;
  float M = -1e30f;
#pragma unroll
  for (int ch = 0; ch < NCHUNK; ch++) M = fmaxf(M, mpart[ch * B + b]);
  float l = 0.f, o = 0.f;
#pragma unroll
  for (int ch = 0; ch < NCHUNK; ch++) {
    float wgt = expf(mpart[ch * B + b] - M);
    l += lpart[ch * B + b] * wgt;
    o += Opart[((size_t)ch * B + b) * TWO_D + c] * wgt;
  }
  af[(size_t)b * TWO_D + c] = o / l;
}

// ---------------------------------------------------------------------------
// per-row step: halting gates, stack machine, VQ, recurrence update
// one 256-thread block per row
// ---------------------------------------------------------------------------
__global__ __launch_bounds__(256) void step_kernel(
    const float* __restrict__ af, float* __restrict__ zf,
    float* __restrict__ stack, float* __restrict__ ptrb,
    float* __restrict__ halting, float* __restrict__ remain,
    float* __restrict__ vq, float* __restrict__ eth,
    float* __restrict__ ponder, float* __restrict__ zw,
    int* __restrict__ cursym, const float* __restrict__ Wh,
    const float* __restrict__ bh, const float* __restrict__ Ws3,
    const float* __restrict__ bs3, const float* __restrict__ codebook,
    const float* __restrict__ cbsq, const float* __restrict__ adjacency,
    int t) {
  const int b = blockIdx.x, tid = threadIdx.x;
  __shared__ float cf_sh[TWO_D];
  __shared__ float r0[256], r1[256], r2[256], r3[256];
  __shared__ float nptr_sh[S_SLOTS], wm_sh[S_SLOTS];
  __shared__ float dist_sh[NSYM];
  __shared__ int idx_sh[NSYM];
  __shared__ float sc_sh[8];

  const float z_c = af[(size_t)b * TWO_D + tid];
  const int cs_old = (t > 0) ? cursym[b] : 0;

  // 4 dots: p_halt pre-act + 3 ctrl logits
  r0[tid] = z_c * Wh[tid];
  r1[tid] = z_c * Ws3[tid];
  r2[tid] = z_c * Ws3[TWO_D + tid];
  r3[tid] = z_c * Ws3[2 * TWO_D + tid];
  __syncthreads();
  for (int s = 128; s > 0; s >>= 1) {
    if (tid < s) {
      r0[tid] += r0[tid + s]; r1[tid] += r1[tid + s];
      r2[tid] += r2[tid + s]; r3[tid] += r3[tid + s];
    }
    __syncthreads();
  }
  if (tid == 0) {
    float ph = 1.f / (1.f + expf(-(r0[0] + bh[0])));
    float l0 = r1[0] + bs3[0], l1 = r2[0] + bs3[1], l2 = r3[0] + bs3[2];
    float mx = fmaxf(l0, fmaxf(l1, l2));
    float e0 = expf(l0 - mx), e1 = expf(l1 - mx), e2 = expf(l2 - mx);
    float inv = 1.f / (e0 + e1 + e2);
    sc_sh[0] = e0 * inv; sc_sh[1] = e1 * inv; sc_sh[2] = e2 * inv;
    sc_sh[3] = ph;
  }
  __syncthreads();
  float push = sc_sh[0], pop = sc_sh[1], noop = sc_sh[2], p_halt = sc_sh[3];
  if (tid < S_SLOTS) {
    float pc = ptrb[b * S_SLOTS + tid];
    float pu = ptrb[b * S_SLOTS + ((tid + 15) & 15)];
    float pd = ptrb[b * S_SLOTS + ((tid + 1) & 15)];
    float raw = push * pu + pop * pd + noop * pc;
    float wmv = push * pu;
    float ssum = raw;
    for (int off = 1; off < 16; off <<= 1) ssum += __shfl_xor(ssum, off);
    float np_ = raw / (ssum + EPS);
    nptr_sh[tid] = np_;
    wm_sh[tid] = wmv;
    ptrb[b * S_SLOTS + tid] = np_;
  }
  __syncthreads();
  // stack update + read
  float acc = 0.f;
#pragma unroll
  for (int s = 0; s < S_SLOTS; s++) {
    size_t ix = ((size_t)(b * S_SLOTS + s)) * TWO_D + tid;
    float v = stack[ix];
    float wv = wm_sh[s];
    v = wv * z_c + v * (1.f - wv);
    stack[ix] = v;
    acc += v * nptr_sh[s];
  }
  float cf_c = z_c + acc;
  cf_sh[tid] = cf_c;
  r0[tid] = cf_c * cf_c;
  __syncthreads();
  for (int s = 128; s > 0; s >>= 1) {
    if (tid < s) r0[tid] += r0[tid + s];
    __syncthreads();
  }
  float cfsq = r0[0];
  // distances over 128 symbols
  if (tid < NSYM) {
    const float* cb = codebook + (size_t)tid * TWO_D;
    float dot = 0.f;
#pragma unroll 8
    for (int c = 0; c < TWO_D; c++) dot += cf_sh[c] * cb[c];
    float dval = cfsq + cbsq[tid] - 2.f * dot;
    if (t > 0) {
      float a = adjacency[cs_old * NSYM + tid];
      dval -= GBS * (1.f / (1.f + expf(-a)));
    }
    dist_sh[tid] = dval;
    idx_sh[tid] = tid;
  }
  __syncthreads();
  for (int s = 64; s > 0; s >>= 1) {
    if (tid < s) {
      float dA = dist_sh[tid], dB = dist_sh[tid + s];
      int iA = idx_sh[tid], iB = idx_sh[tid + s];
      if (dB < dA || (dB == dA && iB < iA)) {
        dist_sh[tid] = dB; idx_sh[tid] = iB;
      }
    }
    __syncthreads();
  }
  const int sym = idx_sh[0];
  const float zq_c = codebook[(size_t)sym * TWO_D + tid];
  float diff = zq_c - cf_c;
  r1[tid] = diff * diff;
  r2[tid] = (t > 0 && tid < NSYM) ? adjacency[cs_old * NSYM + tid] : -1e30f;
  __syncthreads();
  for (int s = 128; s > 0; s >>= 1) {
    if (tid < s) {
      r1[tid] += r1[tid + s];
      r2[tid] = fmaxf(r2[tid], r2[tid + s]);
    }
    __syncthreads();
  }
  float amax = r2[0];
  r3[tid] = (t > 0 && tid < NSYM) ? expf(adjacency[cs_old * NSYM + tid] - amax)
                                  : 0.f;
  __syncthreads();
  for (int s = 128; s > 0; s >>= 1) {
    if (tid < s) r3[tid] += r3[tid + s];
    __syncthreads();
  }
  if (tid == 0) {
    float vql = (1.f + CC) * (r1[0] * (1.f / (float)TWO_D));
    float h = halting[b], rem = remain[b];
    float still = (h < ACT_TH) ? 1.f : 0.f;
    float p = (t == T_STEPS - 1) ? rem : p_halt * still;
    halting[b] = h + p;
    remain[b] = rem - p;
    ponder[b] += still;
    vq[b] += vql;
    if (t > 0) {
      float asym = adjacency[cs_old * NSYM + sym];
      eth[b] += (amax + logf(r3[0]) - asym);
    }
    cursym[b] = sym;
    sc_sh[4] = p;
  }
  __syncthreads();
  float p = sc_sh[4];
  float znew = 0.7f * cf_c + 0.3f * zq_c;
  zf[(size_t)b * TWO_D + tid] = znew;
  zw[(size_t)b * TWO_D + tid] += p * znew;
}

// ---------------------------------------------------------------------------
// final logits + scalar outputs
// ---------------------------------------------------------------------------
__global__ __launch_bounds__(128) void logits_kernel(
    const float* __restrict__ zw, const float* __restrict__ Wd,
    const float* __restrict__ bd, const float* __restrict__ vq,
    const float* __restrict__ eth, const float* __restrict__ ponder,
    float* __restrict__ out) {
  int b = blockIdx.x, tid = threadIdx.x;
  __shared__ float zsh[TWO_D];
  zsh[tid] = zw[(size_t)b * TWO_D + tid];
  zsh[tid + D] = zw[(size_t)b * TWO_D + D + tid];
  __syncthreads();
  const float* wrow = Wd + (size_t)tid * TWO_D;
  float dot = 0.f;
#pragma unroll 8
  for (int c = 0; c < TWO_D; c++) dot += zsh[c] * wrow[c];
  out[(size_t)b * V_OUT + tid] = dot + bd[tid];
  if (tid == 0) {
    out[(size_t)B * V_OUT + b] = vq[b];
    out[(size_t)B * V_OUT + B + b] = eth[b];
    out[(size_t)B * V_OUT + 2 * B + b] = ponder[b];
  }
}

// ---------------------------------------------------------------------------
extern "C" void kernel_launch(void* const* d_in, const int* in_sizes, int n_in,
                              void* d_out, int out_size, void* d_ws,
                              size_t ws_size, hipStream_t stream) {
  const int* input_ids = (const int*)d_in[0];
  const float* emb_mag = (const float*)d_in[1];
  const float* emb_phase = (const float*)d_in[2];
  const float* cell_Wr = (const float*)d_in[3];
  const float* cell_Wi = (const float*)d_in[4];
  const float* ln_scale = (const float*)d_in[5];
  const float* ln_shift = (const float*)d_in[6];
  const float* mod_bias = (const float*)d_in[7];
  const float* Wh = (const float*)d_in[8];
  const float* bh = (const float*)d_in[9];
  const float* Ws3 = (const float*)d_in[10];
  const float* bs3 = (const float*)d_in[11];
  const float* Wq_r = (const float*)d_in[12];
  const float* Wq_i = (const float*)d_in[13];
  const float* Wk_r = (const float*)d_in[14];
  const float* Wk_i = (const float*)d_in[15];
  const float* Wv_r = (const float*)d_in[16];
  const float* Wv_i = (const float*)d_in[17];
  const float* codebook = (const float*)d_in[18];
  const float* adjacency = (const float*)d_in[19];
  const float* Wd = (const float*)d_in[20];
  const float* bd = (const float*)d_in[21];
  float* out = (float*)d_out;

  float* w = (float*)d_ws;
  size_t off = 0;
  float* cellW = w + off; off += 256 * 256;
  float* qkvW = w + off;  off += 768 * 256;
  float* cbsq = w + off;  off += 128;
  float* zf = w + off;    off += (size_t)B * TWO_D;
  float* pf = w + off;    off += (size_t)B * TWO_D;
  float* qkvF = w + off;  off += (size_t)3 * B * TWO_D;
  float* af = w + off;    off += (size_t)B * TWO_D;
  float* zw = w + off;    off += (size_t)B * TWO_D;
  float* Opart = w + off; off += (size_t)NCHUNK * B * TWO_D;
  float* mpart = w + off; off += (size_t)NCHUNK * B;
  float* lpart = w + off; off += (size_t)NCHUNK * B;
  float* ptrb = w + off;  off += (size_t)B * S_SLOTS;
  float* halting = w + off; off += B;
  float* remain = w + off;  off += B;
  float* vqb = w + off;     off += B;
  float* ethb = w + off;    off += B;
  float* ponderb = w + off; off += B;
  int* cursym = (int*)(w + off); off += B;
  float* stack = w + off; off += (size_t)B * S_SLOTS * TWO_D;

  build_weights<<<256, 256, 0, stream>>>(cell_Wr, cell_Wi, Wq_r, Wq_i, Wk_r,
                                         Wk_i, Wv_r, Wv_i, codebook, cellW,
                                         qkvW, cbsq);
  init_state<<<B, 128, 0, stream>>>(input_ids, emb_mag, emb_phase, zf, ptrb,
                                    halting, remain, vqb, ethb, ponderb, zw,
                                    stack);
  for (int t = 0; t < T_STEPS; t++) {
    gemm_rowmajor_bt<<<dim3(B / 64, 4), 256, 0, stream>>>(zf, cellW, pf);
    cnorm_modrelu<<<B, 128, 0, stream>>>(pf, ln_scale, ln_shift, mod_bias);
    gemm_rowmajor_bt<<<dim3(B / 64, 12), 256, 0, stream>>>(pf, qkvW, qkvF);
    flash_attn<<<dim3(B / 64, NCHUNK), 256, 0, stream>>>(
        qkvF, qkvF + (size_t)B * TWO_D, qkvF + (size_t)2 * B * TWO_D, Opart,
        mpart, lpart);
    merge_attn<<<B, 256, 0, stream>>>(Opart, mpart, lpart, af);
    step_kernel<<<B, 256, 0, stream>>>(af, zf, stack, ptrb, halting, remain,
                                       vqb, ethb, ponderb, zw, cursym, Wh, bh,
                                       Ws3, bs3, codebook, cbsq, adjacency, t);
  }
  logits_kernel<<<B, 128, 0, stream>>>(zw, Wd, bd, vqb, ethb, ponderb, out);
}

// Round 5
// 2857.286 us; speedup vs baseline: 1.5850x; 1.5850x over previous
//
#include <hip/hip_runtime.h>
#include <hip/hip_bf16.h>
#include <math.h>

#define B 4096
#define D 128
#define TWO_D 256
#define S_SLOTS 16
#define NSYM 128
#define V_OUT 128
#define T_STEPS 8
#define EPS 1e-6f
#define ACT_TH 0.9999f
#define GBS 0.8f
#define CC 0.01f
#define SCALE 0.08838834764831845f  // D^-0.5

#define NCHUNK 4
#define CHUNK (B / NCHUNK)  // 1024
#define QT 32               // q-rows per flash block
#define KT 64               // keys per K-tile

typedef short s16x8 __attribute__((ext_vector_type(8)));
typedef float f32x4 __attribute__((ext_vector_type(4)));
#define MFMA16(A, Bb, C) __builtin_amdgcn_mfma_f32_16x16x32_bf16(A, Bb, C, 0, 0, 0)

__device__ __forceinline__ unsigned short f2bf(float x) {
  __bf16 h = (__bf16)x;
  return *(unsigned short*)&h;
}
__device__ __forceinline__ float bf2f(unsigned short u) {
  __bf16 h = *(__bf16*)&u;
  return (float)h;
}

// ---------------------------------------------------------------------------
// combined real-ified complex weights W' = [[Wr,-Wi],[Wi,Wr]] -> bf16 hi/lo
// ---------------------------------------------------------------------------
__device__ __forceinline__ float combine_w(const float* __restrict__ Wr,
                                           const float* __restrict__ Wi,
                                           int j, int k) {
  if (j < D) return (k < D) ? Wr[j * D + k] : -Wi[j * D + (k - D)];
  return (k < D) ? Wi[(j - D) * D + k] : Wr[(j - D) * D + (k - D)];
}

__global__ __launch_bounds__(256) void build_weights(
    const float* __restrict__ cell_Wr, const float* __restrict__ cell_Wi,
    const float* __restrict__ Wq_r, const float* __restrict__ Wq_i,
    const float* __restrict__ Wk_r, const float* __restrict__ Wk_i,
    const float* __restrict__ Wv_r, const float* __restrict__ Wv_i,
    const float* __restrict__ codebook,
    unsigned short* __restrict__ cellWH, unsigned short* __restrict__ cellWL,
    unsigned short* __restrict__ qkvWH, unsigned short* __restrict__ qkvWL,
    float* __restrict__ cbsq) {
  int e = blockIdx.x * 256 + threadIdx.x;  // 0..65535
  int j = e >> 8, k = e & 255;
  float v = combine_w(cell_Wr, cell_Wi, j, k);
  unsigned short hh = f2bf(v);
  cellWH[e] = hh; cellWL[e] = f2bf(v - bf2f(hh));
  v = combine_w(Wq_r, Wq_i, j, k);
  hh = f2bf(v); qkvWH[e] = hh; qkvWL[e] = f2bf(v - bf2f(hh));
  v = combine_w(Wk_r, Wk_i, j, k);
  hh = f2bf(v); qkvWH[65536 + e] = hh; qkvWL[65536 + e] = f2bf(v - bf2f(hh));
  v = combine_w(Wv_r, Wv_i, j, k);
  hh = f2bf(v); qkvWH[131072 + e] = hh; qkvWL[131072 + e] = f2bf(v - bf2f(hh));
  if (blockIdx.x == 0 && threadIdx.x < NSYM) {
    float s = 0.f;
    for (int c = 0; c < TWO_D; c++) {
      float cv = codebook[threadIdx.x * TWO_D + c];
      s += cv * cv;
    }
    cbsq[threadIdx.x] = s;
  }
}

// ---------------------------------------------------------------------------
// init: embedding -> zf (bf16 hi/lo) ; zero zw/stack ; ptr one-hot ; scalars
// ---------------------------------------------------------------------------
__global__ __launch_bounds__(128) void init_state(
    const int* __restrict__ input_ids, const float* __restrict__ emb_mag,
    const float* __restrict__ emb_phase,
    unsigned short* __restrict__ zfH, unsigned short* __restrict__ zfL,
    float* __restrict__ ptrb, float* __restrict__ halting,
    float* __restrict__ remain, float* __restrict__ vq,
    float* __restrict__ eth, float* __restrict__ ponder,
    float* __restrict__ zw, float* __restrict__ stack) {
  int b = blockIdx.x, tid = threadIdx.x;
  int idx = input_ids[b];
  float rr = emb_mag[idx * D + tid];
  float th = emb_phase[idx * D + tid];
  float zr = rr * cosf(th), zi = rr * sinf(th);
  unsigned short hh = f2bf(zr);
  zfH[(size_t)b * TWO_D + tid] = hh;
  zfL[(size_t)b * TWO_D + tid] = f2bf(zr - bf2f(hh));
  hh = f2bf(zi);
  zfH[(size_t)b * TWO_D + D + tid] = hh;
  zfL[(size_t)b * TWO_D + D + tid] = f2bf(zi - bf2f(hh));
  zw[(size_t)b * TWO_D + tid] = 0.f;
  zw[(size_t)b * TWO_D + D + tid] = 0.f;
  if (tid < S_SLOTS) ptrb[b * S_SLOTS + tid] = (tid == 0) ? 1.f : 0.f;
  if (tid == 0) {
    halting[b] = 0.f; remain[b] = 1.f;
    vq[b] = 0.f; eth[b] = 0.f; ponder[b] = 0.f;
  }
  for (int k = tid; k < S_SLOTS * TWO_D; k += 128)
    stack[(size_t)b * S_SLOTS * TWO_D + k] = 0.f;
}

// ---------------------------------------------------------------------------
// MFMA GEMM: C[m][n] = sum_k A[m][k]*W[n][k], bf16 hi/lo split (3 terms).
// grid (B/32, N/64), 256 thr = 4 waves. wave: m-half (w&1)*16, n-half (w>>1)*32.
// MODE 0: write f32 C. MODE 1: qkv epilogue (q scaled+split, k split, v -> vt).
// ---------------------------------------------------------------------------
template <int MODE>
__global__ __launch_bounds__(256) void gemm_mfma(
    const unsigned short* __restrict__ AH, const unsigned short* __restrict__ AL,
    const unsigned short* __restrict__ WH, const unsigned short* __restrict__ WL,
    float* __restrict__ Cf,
    unsigned short* __restrict__ qH_, unsigned short* __restrict__ qL_,
    unsigned short* __restrict__ kH_, unsigned short* __restrict__ kL_,
    unsigned short* __restrict__ vtH_, unsigned short* __restrict__ vtL_) {
  const int tid = threadIdx.x;
  const int w = tid >> 6, lane = tid & 63, r = lane & 15, h = lane >> 4;
  const int m0 = blockIdx.x * 32 + (w & 1) * 16;
  const int n0g = blockIdx.y * 64 + (w >> 1) * 32;
  f32x4 acc[2];
  acc[0] = f32x4{0.f, 0.f, 0.f, 0.f};
  acc[1] = f32x4{0.f, 0.f, 0.f, 0.f};
  const size_t abase = (size_t)(m0 + r) * TWO_D;
  const size_t wb0 = (size_t)(n0g + r) * TWO_D;
  const size_t wb1 = (size_t)(n0g + 16 + r) * TWO_D;
#pragma unroll
  for (int kf = 0; kf < 8; kf++) {
    s16x8 ah = *(const s16x8*)&AH[abase + kf * 32 + h * 8];
    s16x8 al = *(const s16x8*)&AL[abase + kf * 32 + h * 8];
    s16x8 b0h = *(const s16x8*)&WH[wb0 + kf * 32 + h * 8];
    s16x8 b0l = *(const s16x8*)&WL[wb0 + kf * 32 + h * 8];
    s16x8 b1h = *(const s16x8*)&WH[wb1 + kf * 32 + h * 8];
    s16x8 b1l = *(const s16x8*)&WL[wb1 + kf * 32 + h * 8];
    acc[0] = MFMA16(ah, b0h, acc[0]);
    acc[0] = MFMA16(ah, b0l, acc[0]);
    acc[0] = MFMA16(al, b0h, acc[0]);
    acc[1] = MFMA16(ah, b1h, acc[1]);
    acc[1] = MFMA16(ah, b1l, acc[1]);
    acc[1] = MFMA16(al, b1h, acc[1]);
  }
#pragma unroll
  for (int ct = 0; ct < 2; ct++) {
    int col = n0g + ct * 16 + r;
#pragma unroll
    for (int reg = 0; reg < 4; reg++) {
      int row = m0 + h * 4 + reg;
      float val = acc[ct][reg];
      if (MODE == 0) {
        Cf[(size_t)row * TWO_D + col] = val;
      } else {
        int buf = col >> 8;
        int c = col & 255;
        if (buf == 0) {
          float v2 = val * SCALE;
          unsigned short hh = f2bf(v2);
          qH_[(size_t)row * TWO_D + c] = hh;
          qL_[(size_t)row * TWO_D + c] = f2bf(v2 - bf2f(hh));
        } else if (buf == 1) {
          unsigned short hh = f2bf(val);
          kH_[(size_t)row * TWO_D + c] = hh;
          kL_[(size_t)row * TWO_D + c] = f2bf(val - bf2f(hh));
        } else {
          unsigned short hh = f2bf(val);
          vtH_[(size_t)c * B + row] = hh;
          vtL_[(size_t)c * B + row] = f2bf(val - bf2f(hh));
        }
      }
    }
  }
}

// ---------------------------------------------------------------------------
// cnorm + modrelu: read f32 pf, write bf16 hi/lo pfH/pfL
// ---------------------------------------------------------------------------
__global__ __launch_bounds__(128) void cnorm_modrelu(
    const float* __restrict__ pf, const float* __restrict__ ln_scale,
    const float* __restrict__ ln_shift, const float* __restrict__ mod_bias,
    unsigned short* __restrict__ pfH, unsigned short* __restrict__ pfL) {
  int b = blockIdx.x, d = threadIdx.x;
  __shared__ float red[128];
  float pr = pf[(size_t)b * TWO_D + d];
  float pi = pf[(size_t)b * TWO_D + D + d];
  float h = sqrtf(pr * pr + pi * pi);
  float mag = h + EPS;
  red[d] = mag;
  __syncthreads();
  for (int s = 64; s > 0; s >>= 1) {
    if (d < s) red[d] += red[d + s];
    __syncthreads();
  }
  float mean = red[0] * (1.f / 128.f);
  __syncthreads();
  float dm = mag - mean;
  red[d] = dm * dm;
  __syncthreads();
  for (int s = 64; s > 0; s >>= 1) {
    if (d < s) red[d] += red[d + s];
    __syncthreads();
  }
  float var = red[0] * (1.f / 127.f);
  float nm = dm * (1.f / sqrtf(var + EPS)) * ln_scale[d] + ln_shift[d];
  float cph, sph;
  if (h > 0.f) { cph = pr / h; sph = pi / h; } else { cph = 1.f; sph = 0.f; }
  float zr = nm * cph, zi = nm * sph;
  float norm = sqrtf(zr * zr + zi * zi) + EPS;
  float s = fmaxf(norm + mod_bias[d], 0.f) / norm;
  float or_ = zr * s, oi_ = zi * s;
  unsigned short hh = f2bf(or_);
  pfH[(size_t)b * TWO_D + d] = hh;
  pfL[(size_t)b * TWO_D + d] = f2bf(or_ - bf2f(hh));
  hh = f2bf(oi_);
  pfH[(size_t)b * TWO_D + D + d] = hh;
  pfL[(size_t)b * TWO_D + D + d] = f2bf(oi_ - bf2f(hh));
}

// ---------------------------------------------------------------------------
// MFMA flash attention, bf16 hi/lo split. grid (B/QT, NCHUNK), 256 thr = 4 waves.
// wave w: S-role = q-half (w&1), key-half (w>>1); PV-role = dim-quarter w.
// K/V fragments loaded directly from global (L2-hot); only P goes via LDS.
// ---------------------------------------------------------------------------
__global__ __launch_bounds__(256) void flash_mfma(
    const unsigned short* __restrict__ qH, const unsigned short* __restrict__ qL,
    const unsigned short* __restrict__ kH, const unsigned short* __restrict__ kL,
    const unsigned short* __restrict__ vtH, const unsigned short* __restrict__ vtL,
    float* __restrict__ Opart, float* __restrict__ mpart,
    float* __restrict__ lpart) {
  __shared__ float m_lds[QT], corr_lds[QT];
  __shared__ float wmax[QT][2], lpart_lds[QT][2];
  __shared__ unsigned short Ph[QT][72], Pl[QT][72];  // 144B rows, 16B aligned
  const int tid = threadIdx.x;
  const int w = tid >> 6, lane = tid & 63;
  const int r = lane & 15, h = lane >> 4;
  const int qt = w & 1, kh = w >> 1;
  const int q0 = blockIdx.x * QT;
  const int chunk = blockIdx.y;

  // preload Q A-frags (scale already folded in)
  s16x8 qfh[8], qfl[8];
  {
    const size_t base = (size_t)(q0 + qt * 16 + r) * TWO_D;
#pragma unroll
    for (int kf = 0; kf < 8; kf++) {
      qfh[kf] = *(const s16x8*)&qH[base + kf * 32 + h * 8];
      qfl[kf] = *(const s16x8*)&qL[base + kf * 32 + h * 8];
    }
  }
  f32x4 o[2][4];
#pragma unroll
  for (int qi = 0; qi < 2; qi++)
#pragma unroll
    for (int dt = 0; dt < 4; dt++) o[qi][dt] = f32x4{0.f, 0.f, 0.f, 0.f};
  float l_loc[4] = {0.f, 0.f, 0.f, 0.f};
  if (tid < QT) m_lds[tid] = -1e30f;
  __syncthreads();

  for (int kt = 0; kt < CHUNK / KT; kt++) {
    const int j0 = chunk * CHUNK + kt * KT;
    // ---- S = Q @ K^T (wave: 16q x 32k) ----
    f32x4 sacc[2];
    sacc[0] = f32x4{0.f, 0.f, 0.f, 0.f};
    sacc[1] = f32x4{0.f, 0.f, 0.f, 0.f};
    const size_t kb0 = (size_t)(j0 + kh * 32 + r) * TWO_D;
    const size_t kb1 = (size_t)(j0 + kh * 32 + 16 + r) * TWO_D;
#pragma unroll
    for (int kf = 0; kf < 8; kf++) {
      s16x8 b0h = *(const s16x8*)&kH[kb0 + kf * 32 + h * 8];
      s16x8 b0l = *(const s16x8*)&kL[kb0 + kf * 32 + h * 8];
      s16x8 b1h = *(const s16x8*)&kH[kb1 + kf * 32 + h * 8];
      s16x8 b1l = *(const s16x8*)&kL[kb1 + kf * 32 + h * 8];
      sacc[0] = MFMA16(qfh[kf], b0h, sacc[0]);
      sacc[0] = MFMA16(qfh[kf], b0l, sacc[0]);
      sacc[0] = MFMA16(qfl[kf], b0h, sacc[0]);
      sacc[1] = MFMA16(qfh[kf], b1h, sacc[1]);
      sacc[1] = MFMA16(qfh[kf], b1l, sacc[1]);
      sacc[1] = MFMA16(qfl[kf], b1h, sacc[1]);
    }
    // ---- partial rowmax over wave's 32 cols ----
#pragma unroll
    for (int reg = 0; reg < 4; reg++) {
      float v = fmaxf(sacc[0][reg], sacc[1][reg]);
      v = fmaxf(v, __shfl_xor(v, 1));
      v = fmaxf(v, __shfl_xor(v, 2));
      v = fmaxf(v, __shfl_xor(v, 4));
      v = fmaxf(v, __shfl_xor(v, 8));
      if (r == 0) wmax[qt * 16 + h * 4 + reg][kh] = v;
    }
    __syncthreads();
    // ---- m update + corr (each wave owns 8 rows) ----
    if (lane < 8) {
      int row = w * 8 + lane;
      float mo = m_lds[row];
      float mn = fmaxf(mo, fmaxf(wmax[row][0], wmax[row][1]));
      corr_lds[row] = __expf(mo - mn);
      m_lds[row] = mn;
    }
    __syncthreads();
    // ---- P = exp(S-m), l update, P->LDS (hi/lo), O rescale ----
#pragma unroll
    for (int reg = 0; reg < 4; reg++) {
      int row = qt * 16 + h * 4 + reg;
      float mrow = m_lds[row];
      float p0 = __expf(sacc[0][reg] - mrow);
      float p1 = __expf(sacc[1][reg] - mrow);
      float rs = p0 + p1;
      rs += __shfl_xor(rs, 1);
      rs += __shfl_xor(rs, 2);
      rs += __shfl_xor(rs, 4);
      rs += __shfl_xor(rs, 8);
      l_loc[reg] = l_loc[reg] * corr_lds[row] + rs;
      unsigned short p0h = f2bf(p0), p1h = f2bf(p1);
      Ph[row][kh * 32 + r] = p0h;
      Pl[row][kh * 32 + r] = f2bf(p0 - bf2f(p0h));
      Ph[row][kh * 32 + 16 + r] = p1h;
      Pl[row][kh * 32 + 16 + r] = f2bf(p1 - bf2f(p1h));
    }
#pragma unroll
    for (int qi = 0; qi < 2; qi++)
#pragma unroll
      for (int reg = 0; reg < 4; reg++) {
        float c = corr_lds[qi * 16 + h * 4 + reg];
#pragma unroll
        for (int dt = 0; dt < 4; dt++) o[qi][dt][reg] *= c;
      }
    __syncthreads();
    // ---- O += P @ V (wave: all 32q x its 64 dims) ----
#pragma unroll
    for (int kf2 = 0; kf2 < 2; kf2++) {
      s16x8 pa_h[2], pa_l[2];
#pragma unroll
      for (int qi = 0; qi < 2; qi++) {
        pa_h[qi] = *(const s16x8*)&Ph[qi * 16 + r][kf2 * 32 + h * 8];
        pa_l[qi] = *(const s16x8*)&Pl[qi * 16 + r][kf2 * 32 + h * 8];
      }
#pragma unroll
      for (int dt = 0; dt < 4; dt++) {
        const size_t vb = (size_t)(w * 64 + dt * 16 + r) * B + j0 + kf2 * 32 + h * 8;
        s16x8 vh = *(const s16x8*)&vtH[vb];
        s16x8 vl = *(const s16x8*)&vtL[vb];
#pragma unroll
        for (int qi = 0; qi < 2; qi++) {
          o[qi][dt] = MFMA16(pa_h[qi], vh, o[qi][dt]);
          o[qi][dt] = MFMA16(pa_h[qi], vl, o[qi][dt]);
          o[qi][dt] = MFMA16(pa_l[qi], vh, o[qi][dt]);
        }
      }
    }
    // no barrier needed here: next tile's P/corr writes are fenced by bar1+bar2
  }
  // ---- epilogue: partial l across key-halves, write O/m/l ----
  if (r == 0) {
#pragma unroll
    for (int reg = 0; reg < 4; reg++)
      lpart_lds[qt * 16 + h * 4 + reg][kh] = l_loc[reg];
  }
  __syncthreads();
  const size_t obase = (size_t)chunk * B + q0;
#pragma unroll
  for (int qi = 0; qi < 2; qi++)
#pragma unroll
    for (int reg = 0; reg < 4; reg++) {
      float* dst = &Opart[(obase + qi * 16 + h * 4 + reg) * TWO_D + w * 64 + r];
#pragma unroll
      for (int dt = 0; dt < 4; dt++) dst[dt * 16] = o[qi][dt][reg];
    }
  if (w == 0 && lane < QT) {
    mpart[chunk * B + q0 + lane] = m_lds[lane];
    lpart[chunk * B + q0 + lane] = lpart_lds[lane][0] + lpart_lds[lane][1];
  }
}

__global__ __launch_bounds__(256) void merge_attn(
    const float* __restrict__ Opart, const float* __restrict__ mpart,
    const float* __restrict__ lpart, float* __restrict__ af) {
  int b = blockIdx.x, c = threadIdx.x;
  float M = -1e30f;
#pragma unroll
  for (int ch = 0; ch < NCHUNK; ch++) M = fmaxf(M, mpart[ch * B + b]);
  float l = 0.f, o = 0.f;
#pragma unroll
  for (int ch = 0; ch < NCHUNK; ch++) {
    float wgt = __expf(mpart[ch * B + b] - M);
    l += lpart[ch * B + b] * wgt;
    o += Opart[((size_t)ch * B + b) * TWO_D + c] * wgt;
  }
  af[(size_t)b * TWO_D + c] = o / l;
}

// ---------------------------------------------------------------------------
// per-row step: halting gates, stack machine, VQ, recurrence update
// ---------------------------------------------------------------------------
__global__ __launch_bounds__(256) void step_kernel(
    const float* __restrict__ af, unsigned short* __restrict__ zfH,
    unsigned short* __restrict__ zfL, float* __restrict__ stack,
    float* __restrict__ ptrb, float* __restrict__ halting,
    float* __restrict__ remain, float* __restrict__ vq,
    float* __restrict__ eth, float* __restrict__ ponder,
    float* __restrict__ zw, int* __restrict__ cursym,
    const float* __restrict__ Wh, const float* __restrict__ bh,
    const float* __restrict__ Ws3, const float* __restrict__ bs3,
    const float* __restrict__ codebook, const float* __restrict__ cbsq,
    const float* __restrict__ adjacency, int t) {
  const int b = blockIdx.x, tid = threadIdx.x;
  __shared__ float cf_sh[TWO_D];
  __shared__ float r0[256], r1[256], r2[256], r3[256];
  __shared__ float nptr_sh[S_SLOTS], wm_sh[S_SLOTS];
  __shared__ float dist_sh[NSYM];
  __shared__ int idx_sh[NSYM];
  __shared__ float sc_sh[8];

  const float z_c = af[(size_t)b * TWO_D + tid];
  const int cs_old = (t > 0) ? cursym[b] : 0;

  r0[tid] = z_c * Wh[tid];
  r1[tid] = z_c * Ws3[tid];
  r2[tid] = z_c * Ws3[TWO_D + tid];
  r3[tid] = z_c * Ws3[2 * TWO_D + tid];
  __syncthreads();
  for (int s = 128; s > 0; s >>= 1) {
    if (tid < s) {
      r0[tid] += r0[tid + s]; r1[tid] += r1[tid + s];
      r2[tid] += r2[tid + s]; r3[tid] += r3[tid + s];
    }
    __syncthreads();
  }
  if (tid == 0) {
    float ph = 1.f / (1.f + expf(-(r0[0] + bh[0])));
    float l0 = r1[0] + bs3[0], l1 = r2[0] + bs3[1], l2 = r3[0] + bs3[2];
    float mx = fmaxf(l0, fmaxf(l1, l2));
    float e0 = expf(l0 - mx), e1 = expf(l1 - mx), e2 = expf(l2 - mx);
    float inv = 1.f / (e0 + e1 + e2);
    sc_sh[0] = e0 * inv; sc_sh[1] = e1 * inv; sc_sh[2] = e2 * inv;
    sc_sh[3] = ph;
  }
  __syncthreads();
  float push = sc_sh[0], pop = sc_sh[1], noop = sc_sh[2], p_halt = sc_sh[3];
  if (tid < S_SLOTS) {
    float pc = ptrb[b * S_SLOTS + tid];
    float pu = ptrb[b * S_SLOTS + ((tid + 15) & 15)];
    float pd = ptrb[b * S_SLOTS + ((tid + 1) & 15)];
    float raw = push * pu + pop * pd + noop * pc;
    float wmv = push * pu;
    float ssum = raw;
    for (int off = 1; off < 16; off <<= 1) ssum += __shfl_xor(ssum, off);
    float np_ = raw / (ssum + EPS);
    nptr_sh[tid] = np_;
    wm_sh[tid] = wmv;
    ptrb[b * S_SLOTS + tid] = np_;
  }
  __syncthreads();
  float acc = 0.f;
#pragma unroll
  for (int s = 0; s < S_SLOTS; s++) {
    size_t ix = ((size_t)(b * S_SLOTS + s)) * TWO_D + tid;
    float v = stack[ix];
    float wv = wm_sh[s];
    v = wv * z_c + v * (1.f - wv);
    stack[ix] = v;
    acc += v * nptr_sh[s];
  }
  float cf_c = z_c + acc;
  cf_sh[tid] = cf_c;
  r0[tid] = cf_c * cf_c;
  __syncthreads();
  for (int s = 128; s > 0; s >>= 1) {
    if (tid < s) r0[tid] += r0[tid + s];
    __syncthreads();
  }
  float cfsq = r0[0];
  if (tid < NSYM) {
    const float* cb = codebook + (size_t)tid * TWO_D;
    float dot = 0.f;
#pragma unroll 8
    for (int c = 0; c < TWO_D; c++) dot += cf_sh[c] * cb[c];
    float dval = cfsq + cbsq[tid] - 2.f * dot;
    if (t > 0) {
      float a = adjacency[cs_old * NSYM + tid];
      dval -= GBS * (1.f / (1.f + expf(-a)));
    }
    dist_sh[tid] = dval;
    idx_sh[tid] = tid;
  }
  __syncthreads();
  for (int s = 64; s > 0; s >>= 1) {
    if (tid < s) {
      float dA = dist_sh[tid], dB = dist_sh[tid + s];
      int iA = idx_sh[tid], iB = idx_sh[tid + s];
      if (dB < dA || (dB == dA && iB < iA)) {
        dist_sh[tid] = dB; idx_sh[tid] = iB;
      }
    }
    __syncthreads();
  }
  const int sym = idx_sh[0];
  const float zq_c = codebook[(size_t)sym * TWO_D + tid];
  float diff = zq_c - cf_c;
  r1[tid] = diff * diff;
  r2[tid] = (t > 0 && tid < NSYM) ? adjacency[cs_old * NSYM + tid] : -1e30f;
  __syncthreads();
  for (int s = 128; s > 0; s >>= 1) {
    if (tid < s) {
      r1[tid] += r1[tid + s];
      r2[tid] = fmaxf(r2[tid], r2[tid + s]);
    }
    __syncthreads();
  }
  float amax = r2[0];
  r3[tid] = (t > 0 && tid < NSYM) ? expf(adjacency[cs_old * NSYM + tid] - amax)
                                  : 0.f;
  __syncthreads();
  for (int s = 128; s > 0; s >>= 1) {
    if (tid < s) r3[tid] += r3[tid + s];
    __syncthreads();
  }
  if (tid == 0) {
    float vql = (1.f + CC) * (r1[0] * (1.f / (float)TWO_D));
    float h = halting[b], rem = remain[b];
    float still = (h < ACT_TH) ? 1.f : 0.f;
    float p = (t == T_STEPS - 1) ? rem : p_halt * still;
    halting[b] = h + p;
    remain[b] = rem - p;
    ponder[b] += still;
    vq[b] += vql;
    if (t > 0) {
      float asym = adjacency[cs_old * NSYM + sym];
      eth[b] += (amax + logf(r3[0]) - asym);
    }
    cursym[b] = sym;
    sc_sh[4] = p;
  }
  __syncthreads();
  float p = sc_sh[4];
  float znew = 0.7f * cf_c + 0.3f * zq_c;
  unsigned short hh = f2bf(znew);
  zfH[(size_t)b * TWO_D + tid] = hh;
  zfL[(size_t)b * TWO_D + tid] = f2bf(znew - bf2f(hh));
  zw[(size_t)b * TWO_D + tid] += p * znew;
}

// ---------------------------------------------------------------------------
// final logits + scalar outputs
// ---------------------------------------------------------------------------
__global__ __launch_bounds__(128) void logits_kernel(
    const float* __restrict__ zw, const float* __restrict__ Wd,
    const float* __restrict__ bd, const float* __restrict__ vq,
    const float* __restrict__ eth, const float* __restrict__ ponder,
    float* __restrict__ out) {
  int b = blockIdx.x, tid = threadIdx.x;
  __shared__ float zsh[TWO_D];
  zsh[tid] = zw[(size_t)b * TWO_D + tid];
  zsh[tid + D] = zw[(size_t)b * TWO_D + D + tid];
  __syncthreads();
  const float* wrow = Wd + (size_t)tid * TWO_D;
  float dot = 0.f;
#pragma unroll 8
  for (int c = 0; c < TWO_D; c++) dot += zsh[c] * wrow[c];
  out[(size_t)b * V_OUT + tid] = dot + bd[tid];
  if (tid == 0) {
    out[(size_t)B * V_OUT + b] = vq[b];
    out[(size_t)B * V_OUT + B + b] = eth[b];
    out[(size_t)B * V_OUT + 2 * B + b] = ponder[b];
  }
}

// ---------------------------------------------------------------------------
extern "C" void kernel_launch(void* const* d_in, const int* in_sizes, int n_in,
                              void* d_out, int out_size, void* d_ws,
                              size_t ws_size, hipStream_t stream) {
  const int* input_ids = (const int*)d_in[0];
  const float* emb_mag = (const float*)d_in[1];
  const float* emb_phase = (const float*)d_in[2];
  const float* cell_Wr = (const float*)d_in[3];
  const float* cell_Wi = (const float*)d_in[4];
  const float* ln_scale = (const float*)d_in[5];
  const float* ln_shift = (const float*)d_in[6];
  const float* mod_bias = (const float*)d_in[7];
  const float* Wh = (const float*)d_in[8];
  const float* bh = (const float*)d_in[9];
  const float* Ws3 = (const float*)d_in[10];
  const float* bs3 = (const float*)d_in[11];
  const float* Wq_r = (const float*)d_in[12];
  const float* Wq_i = (const float*)d_in[13];
  const float* Wk_r = (const float*)d_in[14];
  const float* Wk_i = (const float*)d_in[15];
  const float* Wv_r = (const float*)d_in[16];
  const float* Wv_i = (const float*)d_in[17];
  const float* codebook = (const float*)d_in[18];
  const float* adjacency = (const float*)d_in[19];
  const float* Wd = (const float*)d_in[20];
  const float* bd = (const float*)d_in[21];
  float* out = (float*)d_out;

  char* w = (char*)d_ws;
  size_t off = 0;
  auto alloc = [&](size_t bytes) {
    char* p = w + off;
    off += (bytes + 255) & ~(size_t)255;
    return p;
  };
  unsigned short* cellWH = (unsigned short*)alloc(65536 * 2);
  unsigned short* cellWL = (unsigned short*)alloc(65536 * 2);
  unsigned short* qkvWH = (unsigned short*)alloc(3 * 65536 * 2);
  unsigned short* qkvWL = (unsigned short*)alloc(3 * 65536 * 2);
  float* cbsq = (float*)alloc(NSYM * 4);
  unsigned short* zfH = (unsigned short*)alloc((size_t)B * TWO_D * 2);
  unsigned short* zfL = (unsigned short*)alloc((size_t)B * TWO_D * 2);
  float* pf = (float*)alloc((size_t)B * TWO_D * 4);
  unsigned short* pfH = (unsigned short*)alloc((size_t)B * TWO_D * 2);
  unsigned short* pfL = (unsigned short*)alloc((size_t)B * TWO_D * 2);
  unsigned short* qHb = (unsigned short*)alloc((size_t)B * TWO_D * 2);
  unsigned short* qLb = (unsigned short*)alloc((size_t)B * TWO_D * 2);
  unsigned short* kHb = (unsigned short*)alloc((size_t)B * TWO_D * 2);
  unsigned short* kLb = (unsigned short*)alloc((size_t)B * TWO_D * 2);
  unsigned short* vtH = (unsigned short*)alloc((size_t)B * TWO_D * 2);
  unsigned short* vtL = (unsigned short*)alloc((size_t)B * TWO_D * 2);
  float* af = (float*)alloc((size_t)B * TWO_D * 4);
  float* zw_ = (float*)alloc((size_t)B * TWO_D * 4);
  float* Opart = (float*)alloc((size_t)NCHUNK * B * TWO_D * 4);
  float* mpart = (float*)alloc((size_t)NCHUNK * B * 4);
  float* lpart = (float*)alloc((size_t)NCHUNK * B * 4);
  float* ptrb = (float*)alloc((size_t)B * S_SLOTS * 4);
  float* halting = (float*)alloc(B * 4);
  float* remain = (float*)alloc(B * 4);
  float* vqb = (float*)alloc(B * 4);
  float* ethb = (float*)alloc(B * 4);
  float* ponderb = (float*)alloc(B * 4);
  int* cursym = (int*)alloc(B * 4);
  float* stack = (float*)alloc((size_t)B * S_SLOTS * TWO_D * 4);

  build_weights<<<256, 256, 0, stream>>>(cell_Wr, cell_Wi, Wq_r, Wq_i, Wk_r,
                                         Wk_i, Wv_r, Wv_i, codebook, cellWH,
                                         cellWL, qkvWH, qkvWL, cbsq);
  init_state<<<B, 128, 0, stream>>>(input_ids, emb_mag, emb_phase, zfH, zfL,
                                    ptrb, halting, remain, vqb, ethb, ponderb,
                                    zw_, stack);
  for (int t = 0; t < T_STEPS; t++) {
    gemm_mfma<0><<<dim3(B / 32, 4), 256, 0, stream>>>(
        zfH, zfL, cellWH, cellWL, pf, nullptr, nullptr, nullptr, nullptr,
        nullptr, nullptr);
    cnorm_modrelu<<<B, 128, 0, stream>>>(pf, ln_scale, ln_shift, mod_bias, pfH,
                                         pfL);
    gemm_mfma<1><<<dim3(B / 32, 12), 256, 0, stream>>>(
        pfH, pfL, qkvWH, qkvWL, nullptr, qHb, qLb, kHb, kLb, vtH, vtL);
    flash_mfma<<<dim3(B / QT, NCHUNK), 256, 0, stream>>>(
        qHb, qLb, kHb, kLb, vtH, vtL, Opart, mpart, lpart);
    merge_attn<<<B, 256, 0, stream>>>(Opart, mpart, lpart, af);
    step_kernel<<<B, 256, 0, stream>>>(af, zfH, zfL, stack, ptrb, halting,
                                       remain, vqb, ethb, ponderb, zw_, cursym,
                                       Wh, bh, Ws3, bs3, codebook, cbsq,
                                       adjacency, t);
  }
  logits_kernel<<<B, 128, 0, stream>>>(zw_, Wd, bd, vqb, ethb, ponderb, out);
}